// Round 10
// baseline (691.501 us; speedup 1.0000x reference)
//
#include <hip/hip_runtime.h>

#define DEVI static __device__ __forceinline__

typedef __attribute__((ext_vector_type(4))) float f32x4;
typedef __attribute__((ext_vector_type(8))) short short8;
typedef __attribute__((ext_vector_type(4))) short short4v;
typedef __attribute__((ext_vector_type(8))) __bf16 bf16x8;

#define N_    4096
#define KNN_  20
#define NPTS  32768

DEVI unsigned short f2bf(float f){
  unsigned u = __float_as_uint(f);
  u += 0x7FFFu + ((u >> 16) & 1u);
  return (unsigned short)(u >> 16);
}
DEVI float bf2f(unsigned short s){ return __uint_as_float(((unsigned)s) << 16); }
DEVI float bf2fs(short s){ return __uint_as_float(((unsigned)(unsigned short)s) << 16); }
DEVI unsigned umin32(unsigned a, unsigned b){ return a < b ? a : b; }
DEVI unsigned umax32(unsigned a, unsigned b){ return a > b ? a : b; }

DEVI f32x4 mfma16(short8 a, short8 b, f32x4 c){
  return __builtin_amdgcn_mfma_f32_16x16x32_bf16(
      __builtin_bit_cast(bf16x8, a), __builtin_bit_cast(bf16x8, b), c, 0, 0, 0);
}

// LDS row-major bf16 tiles, XOR swizzle on 16B granules (used by lin0)
DEVI short8 lds_frag(const unsigned short* buf, int row, int k0, int strideS, int swzMask){
  return *(const short8*)(buf + row*strideS + (k0 ^ ((row & swzMask) << 3)));
}
DEVI void lds_put8(unsigned short* buf, int row, int k0, int strideS, int swzMask, short8 v){
  *(short8*)(buf + row*strideS + (k0 ^ ((row & swzMask) << 3))) = v;
}

// blind sorted-insert into ascending top-20 (min/max identity, no-op if K>=a[19])
DEVI void ins32(unsigned K, unsigned (&a)[20]){
#pragma unroll
  for (int t = 19; t >= 1; --t) a[t] = umin32(a[t], umax32(a[t-1], K));
  a[0] = umin32(a[0], K);
}
DEVI void ins64(double K, double (&a)[20]){
#pragma unroll
  for (int t = 19; t >= 1; --t) a[t] = fmin(a[t], fmax(a[t-1], K));
  a[0] = fmin(a[0], K);
}

// ---- fused prep: p3 pack (blocks 0..127) + all weight staging (blocks 128..228) ----
DEVI void stage_body(const float* __restrict__ src, unsigned short* __restrict__ dh,
                     unsigned short* __restrict__ dl, int K, int Nw, int KT, int lblk){
  int tid = lblk*256 + (int)threadIdx.x;
  int l = tid & 63;
  int kk = (tid >> 6) % KT;
  int nt = tid / (64*KT);
  int n = nt*16 + (l & 15);
  int kb = kk*32 + ((l >> 4) << 3);
#pragma unroll
  for (int e=0;e<8;++e){
    int k = kb + e;
    float w = (k < K) ? src[(size_t)k*Nw + n] : 0.f;
    unsigned short h = f2bf(w);
    dh[(size_t)tid*8 + e] = h;
    if (dl) dl[(size_t)tid*8 + e] = f2bf(w - bf2f(h));
  }
}

__global__ __launch_bounds__(256) void stage_all_k(const float* __restrict__ pos,
    unsigned short* __restrict__ p3h, unsigned short* __restrict__ p3l, float* __restrict__ nrm3,
    const float* __restrict__ m1w1, const float* __restrict__ m1w2, const float* __restrict__ m1w3,
    const float* __restrict__ m2w1, const float* __restrict__ m2w2, const float* __restrict__ m2w3,
    const float* __restrict__ l0w,
    unsigned short* __restrict__ W1h, unsigned short* __restrict__ W1l,
    unsigned short* __restrict__ W2h, unsigned short* __restrict__ W2l,
    unsigned short* __restrict__ W3h, unsigned short* __restrict__ W3l,
    unsigned short* __restrict__ V1, unsigned short* __restrict__ V2, unsigned short* __restrict__ V3,
    unsigned short* __restrict__ W0){
  const int blk = blockIdx.x;
  if (blk < 128){
    int p = blk*256 + (int)threadIdx.x;
    float x = pos[(size_t)p*3], y = pos[(size_t)p*3+1], z = pos[(size_t)p*3+2];
    float v[8] = {x, y, z, 0.f, 0.f, 0.f, 0.f, 0.f};
#pragma unroll
    for (int c = 0; c < 8; ++c){
      unsigned short h = f2bf(v[c]);
      p3h[(size_t)p*8 + c] = h;
      p3l[(size_t)p*8 + c] = f2bf(v[c] - bf2f(h));
    }
    nrm3[p] = fmaf(x, x, fmaf(y, y, z*z));
    return;
  }
  int b = blk - 128;
  if      (b < 1)  stage_body(m1w1, W1h, W1l, 6,   64,  1, b);
  else if (b < 3)  stage_body(m1w2, W2h, W2l, 64,  64,  2, b-1);
  else if (b < 5)  stage_body(m1w3, W3h, W3l, 64,  64,  2, b-3);
  else if (b < 13) stage_body(m2w1, V1, nullptr, 128, 128, 4, b-5);
  else if (b < 21) stage_body(m2w2, V2, nullptr, 128, 128, 4, b-13);
  else if (b < 37) stage_body(m2w3, V3, nullptr, 128, 256, 4, b-21);
  else             stage_body(l0w,  W0, nullptr, 256, 512, 8, b-37);
}

// ---- KNN: transposed MFMA D[cand][query], direct-global B frags, NO in-loop barriers ----
// grid = 8 batches * 2 chunks * 64 rowtiles = 1024 blocks
// key = (distbits & ~0x7FF) | cid  (cid = candidate id in chunk, 11 bits)
template<int MODE>
__global__ __launch_bounds__(256) void knn_k(const unsigned short* __restrict__ Xh,
                                             const unsigned short* __restrict__ Xl,
                                             const float* __restrict__ nrm,
                                             unsigned* __restrict__ pk){
  __shared__ __align__(16) char smem[15616];
  unsigned* buf    = (unsigned*)(smem);            // [6][256], tid-private columns
  unsigned* rowThr = (unsigned*)(smem + 6144);     // [64]
  unsigned* mD     = (unsigned*)(smem);            // merge overlay (buf/rowThr dead)

  const int blk = blockIdx.x;
  const int rt = blk & 63, ch = (blk >> 6) & 1, bb = blk >> 7;
  const int rowbase = rt * 64, cbase = ch * 2048;
  const size_t gb = (size_t)bb * N_;
  const int tid = threadIdx.x, lane = tid & 63, wid = tid >> 6;
  const int l15 = lane & 15, g = lane >> 4, kL = g << 3, r0 = g << 2;
  const int qidx = wid*16 + l15;

  if (tid < 64) rowThr[tid] = 0xFFFFFFFFu;

  // query fragments (B operand)
  short8 qh0 = {0,0,0,0,0,0,0,0}, qh1 = {0,0,0,0,0,0,0,0};
  short8 ql0 = {0,0,0,0,0,0,0,0}, ql1 = {0,0,0,0,0,0,0,0};
  if (MODE == 1){
    const size_t ab = (gb + rowbase + qidx) * 64;
    qh0 = *(const short8*)(Xh + ab + kL);
    qh1 = *(const short8*)(Xh + ab + 32 + kL);
    ql0 = *(const short8*)(Xl + ab + kL);
    ql1 = *(const short8*)(Xl + ab + 32 + kL);
  } else {
    if (g == 0){
      const size_t ab = (gb + rowbase + qidx) * 8;
      qh0 = *(const short8*)(Xh + ab);
      ql0 = *(const short8*)(Xl + ab);
    }
  }
  const float si = nrm[gb + rowbase + qidx];

  unsigned arr[20];
#pragma unroll
  for (int t = 0; t < 20; ++t) arr[t] = 0xFFFFFFFFu;
  int cnt = 0;
  bool selfR[4];
#pragma unroll
  for (int r = 0; r < 4; ++r) selfR[r] = (l15 == r0 + r);

  __syncthreads();   // rowThr init visible

  for (int c = 0; c < 32; ++c){
    const bool selfTile = (cbase + c*64 == rowbase);
    unsigned kb16[16];
#pragma unroll
    for (int ct = 0; ct < 4; ++ct){
      f32x4 acc = {0.f,0.f,0.f,0.f};
      if (MODE == 1){
        // A-frag: row = base + l15 (cand), k = g*8 (+32 for second)
        const size_t cb64 = (gb + cbase + c*64 + ct*16 + l15) * 64;
        short8 ch0 = *(const short8*)(Xh + cb64 + kL);
        short8 ch1 = *(const short8*)(Xh + cb64 + 32 + kL);
        short8 cl0 = *(const short8*)(Xl + cb64 + kL);
        short8 cl1 = *(const short8*)(Xl + cb64 + 32 + kL);
        acc = mfma16(ch0, qh0, acc); acc = mfma16(ch1, qh1, acc);
        acc = mfma16(cl0, qh0, acc); acc = mfma16(cl1, qh1, acc);
        acc = mfma16(ch0, ql0, acc); acc = mfma16(ch1, ql1, acc);
      } else {
        short8 cb = {0,0,0,0,0,0,0,0}, cl_ = {0,0,0,0,0,0,0,0};
        if (g == 0){
          const size_t cb8 = (size_t)(gb + cbase + c*64 + ct*16 + l15) * 8;
          cb  = *(const short8*)(Xh + cb8);
          cl_ = *(const short8*)(Xl + cb8);
        }
        acc = mfma16(cb,  qh0, acc);
        acc = mfma16(cl_, qh0, acc);
        acc = mfma16(cb,  ql0, acc);
      }
      f32x4 sj4 = *(const f32x4*)(nrm + gb + cbase + c*64 + ct*16 + r0);
#pragma unroll
      for (int r = 0; r < 4; ++r){
        unsigned cid = (unsigned)(c*64 + ct*16 + r0 + r);
        float dv = fmaxf(fmaf(-2.f, acc[r], si + sj4[r]), 0.f);
        unsigned kb = (__float_as_uint(dv) & ~0x7FFu) | cid;
        if (selfTile && ct == wid && selfR[r]) kb = 0x7F800000u | cid;
        kb16[ct*4 + r] = kb;
      }
    }
    // ---- register scan + buffered flush (no barriers) ----
    {
      unsigned thrP = rowThr[qidx];
#pragma unroll
      for (int i = 0; i < 16; ++i){
        unsigned kb = kb16[i];
        if (kb < thrP){
          if (cnt < 6){ buf[cnt*256 + tid] = kb; ++cnt; }
          else ins32(kb, arr);
        }
      }
      for (int t = 0; t < cnt; ++t) ins32(buf[t*256 + tid], arr);
      cnt = 0;
      atomicMin(&rowThr[qidx], arr[19]);
    }
  }
  // ---- merge 4 lane-groups per query -> chunk top-20 ----
  __syncthreads();
  if (g > 0){
#pragma unroll
    for (int t = 0; t < 20; ++t) mD[(qidx*3 + g-1)*20 + t] = arr[t];
  }
  __syncthreads();
  if (g == 0){
    for (int gg = 0; gg < 3; ++gg)
#pragma unroll
      for (int t = 0; t < 20; ++t) ins32(mD[(qidx*3 + gg)*20 + t], arr);
    const size_t gp = gb + rowbase + qidx;
#pragma unroll
    for (int t = 0; t < 20; ++t) pk[((size_t)(ch*20 + t))*NPTS + gp] = arr[t];
  }
}

// ---- merge 2 chunk top-20s -> final idx ----
__global__ __launch_bounds__(256) void knn_merge_k(const unsigned* __restrict__ pk,
                                                   int* __restrict__ idx){
  const int p = blockIdx.x*256 + threadIdx.x;
  double arr[20];
#pragma unroll
  for (int t = 0; t < 20; ++t){
    unsigned k = pk[(size_t)t*NPTS + p];
    unsigned long long K = (((unsigned long long)(k & ~0x7FFu)) << 1) | (k & 0x7FFu);
    arr[t] = __builtin_bit_cast(double, K);
  }
#pragma unroll
  for (int t = 0; t < 20; ++t){
    unsigned k = pk[(size_t)(20 + t)*NPTS + p];
    unsigned long long K = (((unsigned long long)(k & ~0x7FFu)) << 1) | (2048u + (k & 0x7FFu));
    ins64(__builtin_bit_cast(double, K), arr);
  }
  int* o = idx + (size_t)p*KNN_;
#pragma unroll
  for (int t = 0; t < 20; ++t)
    o[t] = (int)(__builtin_bit_cast(unsigned long long, arr[t]) & 0xFFFu);
}

// ------------- EdgeConv1: 6->64->64->64, hi/lo 3-split, fragment-order LDS -------------
__global__ __launch_bounds__(256) void ec1_k(const float* __restrict__ pos, const int* __restrict__ idx1,
    const unsigned short* __restrict__ W1h, const unsigned short* __restrict__ W1l,
    const unsigned short* __restrict__ W2h, const unsigned short* __restrict__ W2l,
    const unsigned short* __restrict__ W3h, const unsigned short* __restrict__ W3l,
    const float* __restrict__ b1, const float* __restrict__ b2, const float* __restrict__ b3,
    unsigned short* __restrict__ x1h, unsigned short* __restrict__ x1l, float* __restrict__ nrm1){
  __shared__ __align__(16) char smem[51200];
  unsigned short* Ah  = (unsigned short*)(smem);            // frag [5][64][8]
  unsigned short* Al  = (unsigned short*)(smem + 5120);
  unsigned short* H1h = (unsigned short*)(smem + 10240);    // frag [5][2][64][8]
  unsigned short* H1l = (unsigned short*)(smem + 20480);
  unsigned short* H2h = (unsigned short*)(smem + 30720);
  unsigned short* H2l = (unsigned short*)(smem + 40960);
  float* dump = (float*)(smem);                             // [80][68] f32 (aliases Ah/Al/H1h, dead)
  const int p0 = blockIdx.x * 4;
  const int bb = p0 >> 12;
  const int tid = threadIdx.x, lane = tid & 63, wid = tid >> 6;
  const int l15 = lane & 15, g = lane >> 4, r0 = g << 2;

  if (tid < 80){ // stage edge features in B-fragment order; zero-fill k>=8
    int p = p0 + tid/20, slot = tid%20;
    int j = idx1[(size_t)p*KNN_ + slot];
    int gj = (bb << 12) + j;
    float a6[6];
    a6[0] = pos[(size_t)p*3]; a6[1] = pos[(size_t)p*3+1]; a6[2] = pos[(size_t)p*3+2];
    a6[3] = pos[(size_t)gj*3]   - a6[0];
    a6[4] = pos[(size_t)gj*3+1] - a6[1];
    a6[5] = pos[(size_t)gj*3+2] - a6[2];
    int mt = tid >> 4, lrow = tid & 15;
    short8 vh, vl, zz = {0,0,0,0,0,0,0,0};
#pragma unroll
    for (int c=0;c<8;++c){
      float v = (c < 6) ? a6[c] : 0.f;
      unsigned short h = f2bf(v);
      vh[c] = (short)h;
      vl[c] = (short)f2bf(v - bf2f(h));
    }
    *(short8*)(Ah + (mt*64 + lrow)*8) = vh;
    *(short8*)(Al + (mt*64 + lrow)*8) = vl;
#pragma unroll
    for (int gg=1;gg<4;++gg){
      *(short8*)(Ah + (mt*64 + gg*16 + lrow)*8) = zz;
      *(short8*)(Al + (mt*64 + gg*16 + lrow)*8) = zz;
    }
  }
  __syncthreads();
  const int nt = wid;
  const int kk2 = nt >> 1, sub2 = (nt & 1)*2 + (g >> 1), e0 = (g & 1)*4;
  { // layer 1 (K=32): A -> H1
    short8 wh = *(const short8*)(W1h + ((size_t)nt*64 + lane)*8);
    short8 wl = *(const short8*)(W1l + ((size_t)nt*64 + lane)*8);
    f32x4 b4 = *(const f32x4*)(b1 + nt*16 + r0);
    for (int mt=0; mt<5; ++mt){
      short8 ah = *(const short8*)(Ah + (mt*64 + lane)*8);
      short8 al = *(const short8*)(Al + (mt*64 + lane)*8);
      f32x4 acc = {0.f,0.f,0.f,0.f};
      acc = mfma16(wh, ah, acc);
      acc = mfma16(wl, ah, acc);
      acc = mfma16(wh, al, acc);
      short4v vh4, vl4;
#pragma unroll
      for (int r=0;r<4;++r){
        float v = fmaxf(acc[r] + b4[r], 0.f);
        unsigned short h = f2bf(v);
        vh4[r] = (short)h;
        vl4[r] = (short)f2bf(v - bf2f(h));
      }
      *(short4v*)(H1h + ((mt*2 + kk2)*64 + sub2*16 + l15)*8 + e0) = vh4;
      *(short4v*)(H1l + ((mt*2 + kk2)*64 + sub2*16 + l15)*8 + e0) = vl4;
    }
  }
  __syncthreads();
  { // layer 2: H1 -> H2
    short8 wh0 = *(const short8*)(W2h + ((size_t)(nt*2+0)*64 + lane)*8);
    short8 wh1 = *(const short8*)(W2h + ((size_t)(nt*2+1)*64 + lane)*8);
    short8 wl0 = *(const short8*)(W2l + ((size_t)(nt*2+0)*64 + lane)*8);
    short8 wl1 = *(const short8*)(W2l + ((size_t)(nt*2+1)*64 + lane)*8);
    f32x4 b4 = *(const f32x4*)(b2 + nt*16 + r0);
    for (int mt=0; mt<5; ++mt){
      short8 ah0 = *(const short8*)(H1h + ((mt*2+0)*64 + lane)*8);
      short8 ah1 = *(const short8*)(H1h + ((mt*2+1)*64 + lane)*8);
      short8 al0 = *(const short8*)(H1l + ((mt*2+0)*64 + lane)*8);
      short8 al1 = *(const short8*)(H1l + ((mt*2+1)*64 + lane)*8);
      f32x4 acc = {0.f,0.f,0.f,0.f};
      acc = mfma16(wh0, ah0, acc); acc = mfma16(wh1, ah1, acc);
      acc = mfma16(wl0, ah0, acc); acc = mfma16(wl1, ah1, acc);
      acc = mfma16(wh0, al0, acc); acc = mfma16(wh1, al1, acc);
      short4v vh4, vl4;
#pragma unroll
      for (int r=0;r<4;++r){
        float v = fmaxf(acc[r] + b4[r], 0.f);
        unsigned short h = f2bf(v);
        vh4[r] = (short)h;
        vl4[r] = (short)f2bf(v - bf2f(h));
      }
      *(short4v*)(H2h + ((mt*2 + kk2)*64 + sub2*16 + l15)*8 + e0) = vh4;
      *(short4v*)(H2l + ((mt*2 + kk2)*64 + sub2*16 + l15)*8 + e0) = vl4;
    }
  }
  __syncthreads();
  { // layer 3: H2 -> f32 dump [80][68]
    short8 wh0 = *(const short8*)(W3h + ((size_t)(nt*2+0)*64 + lane)*8);
    short8 wh1 = *(const short8*)(W3h + ((size_t)(nt*2+1)*64 + lane)*8);
    short8 wl0 = *(const short8*)(W3l + ((size_t)(nt*2+0)*64 + lane)*8);
    short8 wl1 = *(const short8*)(W3l + ((size_t)(nt*2+1)*64 + lane)*8);
    f32x4 b4 = *(const f32x4*)(b3 + nt*16 + r0);
    for (int mt=0; mt<5; ++mt){
      short8 ah0 = *(const short8*)(H2h + ((mt*2+0)*64 + lane)*8);
      short8 ah1 = *(const short8*)(H2h + ((mt*2+1)*64 + lane)*8);
      short8 al0 = *(const short8*)(H2l + ((mt*2+0)*64 + lane)*8);
      short8 al1 = *(const short8*)(H2l + ((mt*2+1)*64 + lane)*8);
      f32x4 acc = {0.f,0.f,0.f,0.f};
      acc = mfma16(wh0, ah0, acc); acc = mfma16(wh1, ah1, acc);
      acc = mfma16(wl0, ah0, acc); acc = mfma16(wl1, ah1, acc);
      acc = mfma16(wh0, al0, acc); acc = mfma16(wh1, al1, acc);
      f32x4 o;
#pragma unroll
      for (int r=0;r<4;++r) o[r] = fmaxf(acc[r] + b4[r], 0.f);
      int edge = mt*16 + l15;
      *(f32x4*)(dump + edge*68 + nt*16 + r0) = o;
    }
  }
  __syncthreads();
  if (tid < 64){ // pool 20 edges per point, 4 channels per thread
    int p = tid >> 4, c4 = tid & 15;
    int st = tid % 20;
    float mx[4] = {0.f,0.f,0.f,0.f};
    for (int e=0;e<20;++e){
      int ee = st + e; if (ee >= 20) ee -= 20;
      f32x4 v = *(const f32x4*)(dump + (p*20 + ee)*68 + c4*4);
#pragma unroll
      for (int r=0;r<4;++r) mx[r] = fmaxf(mx[r], v[r]);
    }
    int gp = p0 + p;
    short4v h4, l4;
    float s = 0.f;
#pragma unroll
    for (int r=0;r<4;++r){
      float m = mx[r];
      unsigned short h = f2bf(m);
      h4[r] = (short)h;
      l4[r] = (short)f2bf(m - bf2f(h));
      s = fmaf(m, m, s);
    }
    *(short4v*)(x1h + (size_t)gp*64 + c4*4) = h4;
    *(short4v*)(x1l + (size_t)gp*64 + c4*4) = l4;
    s += __shfl_xor(s, 1); s += __shfl_xor(s, 2); s += __shfl_xor(s, 4); s += __shfl_xor(s, 8);
    if (c4 == 0) nrm1[gp] = s;
  }
}

// ------------- EdgeConv2: fragment-ordered LDS, swapped-operand MFMA -------------
__global__ __launch_bounds__(256) void ec2_k(const unsigned short* __restrict__ x1h, const int* __restrict__ idx2,
    const unsigned short* __restrict__ V1, const unsigned short* __restrict__ V2, const unsigned short* __restrict__ V3,
    const float* __restrict__ b1, const float* __restrict__ b2, const float* __restrict__ b3,
    unsigned short* __restrict__ x2b){
  __shared__ __align__(16) char smem[81920];
  unsigned short* A  = (unsigned short*)(smem);          // frag [10][4][64][8] 40KB; reused as H2
  unsigned short* H1 = (unsigned short*)(smem + 40960);  // frag 40KB; reused as layer-3 dump
  const int p0 = blockIdx.x * 8, bb = p0 >> 12;
  const int tid = threadIdx.x, lane = tid & 63, wid = tid >> 6;
  const int l15 = lane & 15, r0 = (lane >> 4) << 2;

  if (tid < 160){ // stage edge features in fragment order
    int p = p0 + tid/20, slot = tid%20;
    int j = idx2[(size_t)p*KNN_ + slot];
    int gj = (bb << 12) + j;
    const unsigned short* xi = x1h + (size_t)p*64;
    const unsigned short* xj = x1h + (size_t)gj*64;
    int mt = tid >> 4, lrow = tid & 15;
#pragma unroll
    for (int q=0;q<8;++q){
      short8 vi = *(const short8*)(xi + q*8);
      short8 vj = *(const short8*)(xj + q*8);
      short8 vd;
#pragma unroll
      for (int c=0;c<8;++c) vd[c] = (short)f2bf(bf2fs(vj[c]) - bf2fs(vi[c]));
      *(short8*)(A + (((mt*4 + (q>>2))*64) + (q&3)*16 + lrow)*8) = vi;
      *(short8*)(A + (((mt*4 + 2 + (q>>2))*64) + (q&3)*16 + lrow)*8) = vd;
    }
  }
  __syncthreads();

  { // layer 1: A -> H1
    short8 w[2][4];
#pragma unroll
    for (int ni=0;ni<2;++ni)
#pragma unroll
      for (int kk=0;kk<4;++kk)
        w[ni][kk] = *(const short8*)(V1 + ((size_t)((wid*2+ni)*4+kk)*64 + lane)*8);
    f32x4 b4[2];
    b4[0] = *(const f32x4*)(b1 + (wid*2+0)*16 + r0);
    b4[1] = *(const f32x4*)(b1 + (wid*2+1)*16 + r0);
    for (int mt=0; mt<10; ++mt){
      short8 bfr[4];
#pragma unroll
      for (int kk=0;kk<4;++kk) bfr[kk] = *(const short8*)(A + ((mt*4+kk)*64 + lane)*8);
#pragma unroll
      for (int ni=0;ni<2;++ni){
        int nt = wid*2 + ni;
        f32x4 acc = {0.f,0.f,0.f,0.f};
#pragma unroll
        for (int kk=0;kk<4;++kk) acc = mfma16(w[ni][kk], bfr[kk], acc);
        short4v v4;
#pragma unroll
        for (int r=0;r<4;++r) v4[r] = (short)f2bf(fmaxf(acc[r] + b4[ni][r], 0.f));
        int kk2 = nt >> 1, sub2 = (nt & 1)*2 + (r0 >> 3);
        *(short4v*)(H1 + ((mt*4+kk2)*64 + sub2*16 + l15)*8 + (r0 & 4)) = v4;
      }
    }
  }
  __syncthreads();
  { // layer 2: H1 -> H2 (=A region)
    short8 w[2][4];
#pragma unroll
    for (int ni=0;ni<2;++ni)
#pragma unroll
      for (int kk=0;kk<4;++kk)
        w[ni][kk] = *(const short8*)(V2 + ((size_t)((wid*2+ni)*4+kk)*64 + lane)*8);
    f32x4 b4[2];
    b4[0] = *(const f32x4*)(b2 + (wid*2+0)*16 + r0);
    b4[1] = *(const f32x4*)(b2 + (wid*2+1)*16 + r0);
    for (int mt=0; mt<10; ++mt){
      short8 bfr[4];
#pragma unroll
      for (int kk=0;kk<4;++kk) bfr[kk] = *(const short8*)(H1 + ((mt*4+kk)*64 + lane)*8);
#pragma unroll
      for (int ni=0;ni<2;++ni){
        int nt = wid*2 + ni;
        f32x4 acc = {0.f,0.f,0.f,0.f};
#pragma unroll
        for (int kk=0;kk<4;++kk) acc = mfma16(w[ni][kk], bfr[kk], acc);
        short4v v4;
#pragma unroll
        for (int r=0;r<4;++r) v4[r] = (short)f2bf(fmaxf(acc[r] + b4[ni][r], 0.f));
        int kk2 = nt >> 1, sub2 = (nt & 1)*2 + (r0 >> 3);
        *(short4v*)(A + ((mt*4+kk2)*64 + sub2*16 + l15)*8 + (r0 & 4)) = v4;
      }
    }
  }
  __syncthreads();
  for (int g2=0; g2<2; ++g2){
    {
      short8 w[2][4];
#pragma unroll
      for (int ni=0;ni<2;++ni)
#pragma unroll
        for (int kk=0;kk<4;++kk)
          w[ni][kk] = *(const short8*)(V3 + ((size_t)((g2*8 + wid*2+ni)*4+kk)*64 + lane)*8);
      f32x4 b4[2];
      b4[0] = *(const f32x4*)(b3 + (g2*8 + wid*2+0)*16 + r0);
      b4[1] = *(const f32x4*)(b3 + (g2*8 + wid*2+1)*16 + r0);
      for (int mt=0; mt<10; ++mt){
        short8 bfr[4];
#pragma unroll
        for (int kk=0;kk<4;++kk) bfr[kk] = *(const short8*)(A + ((mt*4+kk)*64 + lane)*8);
#pragma unroll
        for (int ni=0;ni<2;++ni){
          int ntl = wid*2 + ni;
          f32x4 acc = {0.f,0.f,0.f,0.f};
#pragma unroll
          for (int kk=0;kk<4;++kk) acc = mfma16(w[ni][kk], bfr[kk], acc);
          short4v v4;
#pragma unroll
          for (int r=0;r<4;++r) v4[r] = (short)f2bf(fmaxf(acc[r] + b4[ni][r], 0.f));
          int kk2 = ntl >> 1, sub2 = (ntl & 1)*2 + (r0 >> 3);
          *(short4v*)(H1 + ((mt*4+kk2)*64 + sub2*16 + l15)*8 + (r0 & 4)) = v4;
        }
      }
    }
    __syncthreads();
    if (tid < 128){
      int p = tid >> 4, c8 = tid & 15;
      int kk = c8 >> 2, sub = c8 & 3;
      unsigned short mx[8];
#pragma unroll
      for (int e=0;e<8;++e) mx[e] = 0;
      for (int e=0;e<20;++e){
        int ee = e + p + c8; ee -= (ee >= 20) ? 20 : 0; ee -= (ee >= 20) ? 20 : 0;
        int row = p*20 + ee;
        short8 v = *(const short8*)(H1 + (((row>>4)*4 + kk)*64 + sub*16 + (row & 15))*8);
#pragma unroll
        for (int k2=0;k2<8;++k2){
          unsigned short u = (unsigned short)v[k2];
          mx[k2] = u > mx[k2] ? u : mx[k2];
        }
      }
      short8 o;
#pragma unroll
      for (int k2=0;k2<8;++k2) o[k2] = (short)mx[k2];
      *(short8*)(x2b + (size_t)(p0 + p)*256 + g2*128 + c8*8) = o;
    }
    __syncthreads();
  }
}

// ------------- lin0 (256->512) + relu + segment-max into pool -------------
__global__ __launch_bounds__(256) void lin0_k(const unsigned short* __restrict__ x2b, const unsigned short* __restrict__ W0s,
                                              const float* __restrict__ b0, unsigned* __restrict__ pool){
  __shared__ __align__(16) char smem[67584];
  unsigned short* A = (unsigned short*)(smem);        // [128][256] bf16 swizzled
  unsigned* ploc = (unsigned*)(smem + 65536);
  const int blk = blockIdx.x; const size_t row0 = (size_t)blk * 128; const int bb = blk >> 5;
  const int tid = threadIdx.x, lane = tid & 63, wid = tid >> 6;
  for (int it = tid; it < 4096; it += 256){
    int row = it >> 5, q = (it & 31) << 3;
    lds_put8(A, row, q, 256, 7, *(const short8*)(x2b + (row0 + row)*256 + q));
  }
  ploc[tid] = 0u; ploc[tid+256] = 0u;
  __syncthreads();
  const int l15 = lane & 15, kL = (lane >> 4) << 3;
  short8 af[2][8];
#pragma unroll
  for (int m=0;m<2;++m)
#pragma unroll
    for (int kk=0;kk<8;++kk)
      af[m][kk] = lds_frag(A, (wid*2+m)*16 + l15, kk*32 + kL, 256, 7);
  for (int nt=0; nt<32; ++nt){
    f32x4 a0 = {0.f,0.f,0.f,0.f}, a1 = {0.f,0.f,0.f,0.f};
#pragma unroll
    for (int kk=0;kk<8;++kk){
      short8 w = *(const short8*)(W0s + ((size_t)(nt*8+kk)*64 + lane)*8);
      a0 = mfma16(af[0][kk], w, a0);
      a1 = mfma16(af[1][kk], w, a1);
    }
    int col = nt*16 + l15;
    float m = fmaxf(fmaxf(fmaxf(a0[0],a0[1]),fmaxf(a0[2],a0[3])),
                    fmaxf(fmaxf(a1[0],a1[1]),fmaxf(a1[2],a1[3])));
    m = fmaxf(m + b0[col], 0.f);
    atomicMax(&ploc[col], __float_as_uint(m));
  }
  __syncthreads();
  atomicMax(&pool[(size_t)bb*512 + tid], ploc[tid]);
  atomicMax(&pool[(size_t)bb*512 + tid + 256], ploc[tid+256]);
}

// ------------- head: one block per batch row -------------
__global__ __launch_bounds__(256) void head8_k(const unsigned* __restrict__ pool,
    const float* __restrict__ w1, const float* __restrict__ bb1,
    const float* __restrict__ w2, const float* __restrict__ bb2,
    const float* __restrict__ w3, const float* __restrict__ bb3,
    float* __restrict__ out){
  __shared__ float pl[512];
  __shared__ float y1[256];
  __shared__ float y2[256];
  __shared__ float lg[40];
  const int row = blockIdx.x;
  const int tid = threadIdx.x;
  for (int it = tid; it < 512; it += 256) pl[it] = __uint_as_float(pool[row*512 + it]);
  __syncthreads();
  {
    float acc = bb1[tid];
    for (int k=0;k<512;++k) acc = fmaf(pl[k], w1[(size_t)k*256 + tid], acc);
    y1[tid] = fmaxf(acc, 0.f);
  }
  __syncthreads();
  {
    float acc = bb2[tid];
    for (int k=0;k<256;++k) acc = fmaf(y1[k], w2[(size_t)k*256 + tid], acc);
    y2[tid] = fmaxf(acc, 0.f);
  }
  __syncthreads();
  if (tid < 40){
    float acc = bb3[tid];
    for (int k=0;k<256;++k) acc = fmaf(y2[k], w3[(size_t)k*40 + tid], acc);
    lg[tid] = acc;
  }
  __syncthreads();
  if (tid < 40){
    float m = -__builtin_inff();
    for (int c2=0;c2<40;++c2) m = fmaxf(m, lg[c2]);
    float s = 0.f;
    for (int c2=0;c2<40;++c2) s += expf(lg[c2] - m);
    out[row*40 + tid] = lg[tid] - m - logf(s);
  }
}

extern "C" void kernel_launch(void* const* d_in, const int* in_sizes, int n_in,
                              void* d_out, int out_size, void* d_ws, size_t ws_size,
                              hipStream_t stream){
  (void)in_sizes; (void)n_in; (void)out_size; (void)ws_size;
  const float* pos  = (const float*)d_in[0];
  const float* m1w1 = (const float*)d_in[2];  const float* m1b1 = (const float*)d_in[3];
  const float* m1w2 = (const float*)d_in[4];  const float* m1b2 = (const float*)d_in[5];
  const float* m1w3 = (const float*)d_in[6];  const float* m1b3 = (const float*)d_in[7];
  const float* m2w1 = (const float*)d_in[8];  const float* m2b1 = (const float*)d_in[9];
  const float* m2w2 = (const float*)d_in[10]; const float* m2b2 = (const float*)d_in[11];
  const float* m2w3 = (const float*)d_in[12]; const float* m2b3 = (const float*)d_in[13];
  const float* l0w  = (const float*)d_in[14]; const float* l0b  = (const float*)d_in[15];
  const float* l1w  = (const float*)d_in[16]; const float* l1b  = (const float*)d_in[17];
  const float* l2w  = (const float*)d_in[18]; const float* l2b  = (const float*)d_in[19];
  const float* l3w  = (const float*)d_in[20]; const float* l3b  = (const float*)d_in[21];

  char* ws = (char*)d_ws;
  size_t o = 0;
  auto alloc = [&](size_t bytes){ size_t r = o; o += (bytes + 255) & ~(size_t)255; return r; };
  size_t o_idx1 = alloc((size_t)NPTS*20*4);
  size_t o_idx2 = alloc((size_t)NPTS*20*4);
  size_t o_x1h  = alloc((size_t)NPTS*64*2);
  size_t o_x1l  = alloc((size_t)NPTS*64*2);
  size_t o_nrm  = alloc((size_t)NPTS*4);
  size_t o_x2b  = alloc((size_t)NPTS*256*2);
  size_t o_pool = alloc(8*512*4);
  size_t o_p3h  = alloc((size_t)NPTS*8*2);
  size_t o_p3l  = alloc((size_t)NPTS*8*2);
  size_t o_nrm3 = alloc((size_t)NPTS*4);
  size_t o_pk   = alloc((size_t)2*20*NPTS*4);
  size_t o_W1h = alloc(4*1*64*8*2),  o_W1l = alloc(4*1*64*8*2);
  size_t o_W2h = alloc(4*2*64*8*2),  o_W2l = alloc(4*2*64*8*2);
  size_t o_W3h = alloc(4*2*64*8*2),  o_W3l = alloc(4*2*64*8*2);
  size_t o_V1  = alloc(8*4*64*8*2);
  size_t o_V2  = alloc(8*4*64*8*2);
  size_t o_V3  = alloc(16*4*64*8*2);
  size_t o_W0  = alloc(32*8*64*8*2);

  hipMemsetAsync(ws + o_pool, 0, 8*512*4, stream);

  stage_all_k<<<229,256,0,stream>>>(pos,
      (unsigned short*)(ws+o_p3h), (unsigned short*)(ws+o_p3l), (float*)(ws+o_nrm3),
      m1w1, m1w2, m1w3, m2w1, m2w2, m2w3, l0w,
      (unsigned short*)(ws+o_W1h), (unsigned short*)(ws+o_W1l),
      (unsigned short*)(ws+o_W2h), (unsigned short*)(ws+o_W2l),
      (unsigned short*)(ws+o_W3h), (unsigned short*)(ws+o_W3l),
      (unsigned short*)(ws+o_V1), (unsigned short*)(ws+o_V2), (unsigned short*)(ws+o_V3),
      (unsigned short*)(ws+o_W0));

  knn_k<0><<<1024,256,0,stream>>>((const unsigned short*)(ws+o_p3h), (const unsigned short*)(ws+o_p3l),
                                  (const float*)(ws+o_nrm3), (unsigned*)(ws+o_pk));
  knn_merge_k<<<128,256,0,stream>>>((const unsigned*)(ws+o_pk), (int*)(ws+o_idx1));

  ec1_k<<<8192,256,0,stream>>>(pos, (const int*)(ws+o_idx1),
      (const unsigned short*)(ws+o_W1h), (const unsigned short*)(ws+o_W1l),
      (const unsigned short*)(ws+o_W2h), (const unsigned short*)(ws+o_W2l),
      (const unsigned short*)(ws+o_W3h), (const unsigned short*)(ws+o_W3l),
      m1b1, m1b2, m1b3,
      (unsigned short*)(ws+o_x1h), (unsigned short*)(ws+o_x1l), (float*)(ws+o_nrm));

  knn_k<1><<<1024,256,0,stream>>>((const unsigned short*)(ws+o_x1h), (const unsigned short*)(ws+o_x1l),
                                  (const float*)(ws+o_nrm), (unsigned*)(ws+o_pk));
  knn_merge_k<<<128,256,0,stream>>>((const unsigned*)(ws+o_pk), (int*)(ws+o_idx2));

  ec2_k<<<4096,256,0,stream>>>((const unsigned short*)(ws+o_x1h), (const int*)(ws+o_idx2),
      (const unsigned short*)(ws+o_V1), (const unsigned short*)(ws+o_V2), (const unsigned short*)(ws+o_V3),
      m2b1, m2b2, m2b3, (unsigned short*)(ws+o_x2b));

  lin0_k<<<256,256,0,stream>>>((const unsigned short*)(ws+o_x2b), (const unsigned short*)(ws+o_W0),
                               l0b, (unsigned*)(ws+o_pool));

  head8_k<<<8,256,0,stream>>>((const unsigned*)(ws+o_pool), l1w, l1b, l2w, l2b, l3w, l3b, (float*)d_out);
}

// Round 11
// 575.810 us; speedup vs baseline: 1.2009x; 1.2009x over previous
//
#include <hip/hip_runtime.h>

#define DEVI static __device__ __forceinline__

typedef __attribute__((ext_vector_type(4))) float f32x4;
typedef __attribute__((ext_vector_type(8))) short short8;
typedef __attribute__((ext_vector_type(4))) short short4v;
typedef __attribute__((ext_vector_type(8))) __bf16 bf16x8;

#define N_    4096
#define KNN_  20
#define NPTS  32768

DEVI unsigned short f2bf(float f){
  unsigned u = __float_as_uint(f);
  u += 0x7FFFu + ((u >> 16) & 1u);
  return (unsigned short)(u >> 16);
}
DEVI float bf2f(unsigned short s){ return __uint_as_float(((unsigned)s) << 16); }
DEVI float bf2fs(short s){ return __uint_as_float(((unsigned)(unsigned short)s) << 16); }
DEVI unsigned umin32(unsigned a, unsigned b){ return a < b ? a : b; }
DEVI unsigned umax32(unsigned a, unsigned b){ return a > b ? a : b; }

DEVI f32x4 mfma16(short8 a, short8 b, f32x4 c){
  return __builtin_amdgcn_mfma_f32_16x16x32_bf16(
      __builtin_bit_cast(bf16x8, a), __builtin_bit_cast(bf16x8, b), c, 0, 0, 0);
}

// LDS row-major bf16 tiles, XOR swizzle on 16B granules (used by lin0)
DEVI short8 lds_frag(const unsigned short* buf, int row, int k0, int strideS, int swzMask){
  return *(const short8*)(buf + row*strideS + (k0 ^ ((row & swzMask) << 3)));
}
DEVI void lds_put8(unsigned short* buf, int row, int k0, int strideS, int swzMask, short8 v){
  *(short8*)(buf + row*strideS + (k0 ^ ((row & swzMask) << 3))) = v;
}

// blind sorted-insert into ascending top-20 (min/max identity, no-op if K>=a[19])
DEVI void ins32(unsigned K, unsigned (&a)[20]){
#pragma unroll
  for (int t = 19; t >= 1; --t) a[t] = umin32(a[t], umax32(a[t-1], K));
  a[0] = umin32(a[0], K);
}
DEVI void ins64(double K, double (&a)[20]){
#pragma unroll
  for (int t = 19; t >= 1; --t) a[t] = fmin(a[t], fmax(a[t-1], K));
  a[0] = fmin(a[0], K);
}

// ---- fused prep: p3 pack (blocks 0..127) + all weight staging (blocks 128..228) ----
DEVI void stage_body(const float* __restrict__ src, unsigned short* __restrict__ dh,
                     unsigned short* __restrict__ dl, int K, int Nw, int KT, int lblk){
  int tid = lblk*256 + (int)threadIdx.x;
  int l = tid & 63;
  int kk = (tid >> 6) % KT;
  int nt = tid / (64*KT);
  int n = nt*16 + (l & 15);
  int kb = kk*32 + ((l >> 4) << 3);
#pragma unroll
  for (int e=0;e<8;++e){
    int k = kb + e;
    float w = (k < K) ? src[(size_t)k*Nw + n] : 0.f;
    unsigned short h = f2bf(w);
    dh[(size_t)tid*8 + e] = h;
    if (dl) dl[(size_t)tid*8 + e] = f2bf(w - bf2f(h));
  }
}

__global__ __launch_bounds__(256) void stage_all_k(const float* __restrict__ pos,
    unsigned short* __restrict__ p3h, unsigned short* __restrict__ p3l, float* __restrict__ nrm3,
    const float* __restrict__ m1w1, const float* __restrict__ m1w2, const float* __restrict__ m1w3,
    const float* __restrict__ m2w1, const float* __restrict__ m2w2, const float* __restrict__ m2w3,
    const float* __restrict__ l0w,
    unsigned short* __restrict__ W1h, unsigned short* __restrict__ W1l,
    unsigned short* __restrict__ W2h, unsigned short* __restrict__ W2l,
    unsigned short* __restrict__ W3h, unsigned short* __restrict__ W3l,
    unsigned short* __restrict__ V1, unsigned short* __restrict__ V2, unsigned short* __restrict__ V3,
    unsigned short* __restrict__ W0){
  const int blk = blockIdx.x;
  if (blk < 128){
    int p = blk*256 + (int)threadIdx.x;
    float x = pos[(size_t)p*3], y = pos[(size_t)p*3+1], z = pos[(size_t)p*3+2];
    float v[8] = {x, y, z, 0.f, 0.f, 0.f, 0.f, 0.f};
#pragma unroll
    for (int c = 0; c < 8; ++c){
      unsigned short h = f2bf(v[c]);
      p3h[(size_t)p*8 + c] = h;
      p3l[(size_t)p*8 + c] = f2bf(v[c] - bf2f(h));
    }
    nrm3[p] = fmaf(x, x, fmaf(y, y, z*z));
    return;
  }
  int b = blk - 128;
  if      (b < 1)  stage_body(m1w1, W1h, W1l, 6,   64,  1, b);
  else if (b < 3)  stage_body(m1w2, W2h, W2l, 64,  64,  2, b-1);
  else if (b < 5)  stage_body(m1w3, W3h, W3l, 64,  64,  2, b-3);
  else if (b < 13) stage_body(m2w1, V1, nullptr, 128, 128, 4, b-5);
  else if (b < 21) stage_body(m2w2, V2, nullptr, 128, 128, 4, b-13);
  else if (b < 37) stage_body(m2w3, V3, nullptr, 128, 256, 4, b-21);
  else             stage_body(l0w,  W0, nullptr, 256, 512, 8, b-37);
}

// ---- KNN: transposed MFMA D[cand][query], double-buffered LDS B, 1 barrier/tile ----
// float-bit scan filter vs class-ceiling threshold; exact keys on survivors only
template<int MODE>
__global__ __launch_bounds__(256) void knn_k(const unsigned short* __restrict__ Xh,
                                             const unsigned short* __restrict__ Xl,
                                             const float* __restrict__ nrm,
                                             unsigned* __restrict__ pk){
  constexpr int BSTR = MODE ? 4096 : 512;    // shorts per B buffer
  constexpr int OBL  = MODE ? 16384 : 2048;  // byte offset of Bl pair
  constexpr int OBUF = MODE ? 32768 : 4096;
  constexpr int OTHR = OBUF + 6144;          // buf = [6][256] u32
  constexpr int OSQ  = OTHR + 256;           // rowThr[64]
  constexpr int SM   = MODE ? (OSQ + 512) : 15360;   // sqj[2][64]; MODE0 padded for mD
  __shared__ __align__(16) char smem[SM];
  unsigned short* BhA = (unsigned short*)(smem);         // [2][BSTR]
  unsigned short* BlA = (unsigned short*)(smem + OBL);
  unsigned* buf      = (unsigned*)(smem + OBUF);
  unsigned* rowThr   = (unsigned*)(smem + OTHR);
  float* sqjA        = (float*)(smem + OSQ);             // [2][64]
  unsigned* mD       = (unsigned*)(smem);                // merge overlay (all dead)

  const int blk = blockIdx.x;
  const int rt = blk & 63, ch = (blk >> 6) & 1, bb = blk >> 7;
  const int rowbase = rt * 64, cbase = ch * 2048;
  const size_t gb = (size_t)bb * N_;
  const int tid = threadIdx.x, lane = tid & 63, wid = tid >> 6;
  const int l15 = lane & 15, g = lane >> 4, kL = g << 3, r0 = g << 2;
  const int qidx = wid*16 + l15;

  if (tid < 64) rowThr[tid] = 0xFFFFFFFFu;

  short8 qh0 = {0,0,0,0,0,0,0,0}, qh1 = {0,0,0,0,0,0,0,0};
  short8 ql0 = {0,0,0,0,0,0,0,0}, ql1 = {0,0,0,0,0,0,0,0};
  if (MODE == 1){
    const size_t ab = (gb + rowbase + qidx) * 64;
    qh0 = *(const short8*)(Xh + ab + kL);
    qh1 = *(const short8*)(Xh + ab + 32 + kL);
    ql0 = *(const short8*)(Xl + ab + kL);
    ql1 = *(const short8*)(Xl + ab + 32 + kL);
  } else {
    if (g == 0){
      const size_t ab = (gb + rowbase + qidx) * 8;
      qh0 = *(const short8*)(Xh + ab);
      ql0 = *(const short8*)(Xl + ab);
    }
  }
  const float si = nrm[gb + rowbase + qidx];

  unsigned arr[20];
#pragma unroll
  for (int t = 0; t < 20; ++t) arr[t] = 0xFFFFFFFFu;
  int cnt = 0;
  bool selfR[4];
#pragma unroll
  for (int r = 0; r < 4; ++r) selfR[r] = (l15 == r0 + r);

  // prologue: stage tile 0 into buffer 0
  if (MODE == 1){
    for (int f = tid; f < 512; f += 256){
      int lf = f & 63, half = (f >> 6) & 1, ct = f >> 7;
      int row = ct*16 + (lf & 15);
      int col = half*32 + ((lf >> 4) << 3);
      const size_t src = (gb + cbase + row) * 64 + col;
      *(short8*)(BhA + f*8) = *(const short8*)(Xh + src);
      *(short8*)(BlA + f*8) = *(const short8*)(Xl + src);
    }
  } else {
    if (tid < 64)       *(short8*)(BhA + tid*8)      = *(const short8*)(Xh + (gb + cbase + tid)*8);
    else if (tid < 128) *(short8*)(BlA + (tid-64)*8) = *(const short8*)(Xl + (gb + cbase + (tid-64))*8);
  }
  if (tid < 64) sqjA[tid] = nrm[gb + cbase + tid];
  __syncthreads();

  for (int c = 0; c < 32; ++c){
    const int cur = c & 1;
    const unsigned short* Bh = BhA + cur*BSTR;
    const unsigned short* Bl = BlA + cur*BSTR;
    const float* sqj = sqjA + cur*64;
    const bool selfTile = (cbase + c*64 == rowbase);
    const bool more = (c + 1 < 32);

    // ---- issue next-tile global loads into regs (longest overlap window) ----
    short8 nh0 = {0,0,0,0,0,0,0,0}, nh1 = {0,0,0,0,0,0,0,0};
    short8 nl0 = {0,0,0,0,0,0,0,0}, nl1 = {0,0,0,0,0,0,0,0};
    float nsq = 0.f;
    if (more){
      if (MODE == 1){
#pragma unroll
        for (int ff = 0; ff < 2; ++ff){
          int f = tid + ff*256;
          int lf = f & 63, half = (f >> 6) & 1, ct = f >> 7;
          int row = ct*16 + (lf & 15);
          int col = half*32 + ((lf >> 4) << 3);
          const size_t src = (gb + cbase + (c+1)*64 + row) * 64 + col;
          if (ff == 0){ nh0 = *(const short8*)(Xh + src); nl0 = *(const short8*)(Xl + src); }
          else        { nh1 = *(const short8*)(Xh + src); nl1 = *(const short8*)(Xl + src); }
        }
      } else {
        if (tid < 64)       nh0 = *(const short8*)(Xh + (gb + cbase + (c+1)*64 + tid)*8);
        else if (tid < 128) nl0 = *(const short8*)(Xl + (gb + cbase + (c+1)*64 + (tid-64))*8);
      }
      if (tid < 64) nsq = nrm[gb + cbase + (c+1)*64 + tid];
    }

    // ---- MFMA D[cand][query]; store raw dv bits ----
    unsigned kb16[16];
#pragma unroll
    for (int ct = 0; ct < 4; ++ct){
      f32x4 acc = {0.f,0.f,0.f,0.f};
      if (MODE == 1){
        const int fb = lane*8;
        short8 ch0 = *(const short8*)(Bh + (ct*2+0)*512 + fb);
        short8 ch1 = *(const short8*)(Bh + (ct*2+1)*512 + fb);
        short8 cl0 = *(const short8*)(Bl + (ct*2+0)*512 + fb);
        short8 cl1 = *(const short8*)(Bl + (ct*2+1)*512 + fb);
        acc = mfma16(ch0, qh0, acc); acc = mfma16(ch1, qh1, acc);
        acc = mfma16(cl0, qh0, acc); acc = mfma16(cl1, qh1, acc);
        acc = mfma16(ch0, ql0, acc); acc = mfma16(ch1, ql1, acc);
      } else {
        short8 cb = {0,0,0,0,0,0,0,0}, cl_ = {0,0,0,0,0,0,0,0};
        if (g == 0){
          cb  = *(const short8*)(Bh + (ct*16 + l15)*8);
          cl_ = *(const short8*)(Bl + (ct*16 + l15)*8);
        }
        acc = mfma16(cb,  qh0, acc);
        acc = mfma16(cl_, qh0, acc);
        acc = mfma16(cb,  ql0, acc);
      }
      f32x4 sj4 = *(const f32x4*)(sqj + ct*16 + r0);
#pragma unroll
      for (int r = 0; r < 4; ++r){
        float dv = fmaxf(fmaf(-2.f, acc[r], si + sj4[r]), 0.f);
        kb16[ct*4 + r] = __float_as_uint(dv);
      }
    }

    // ---- scan: float-bit filter vs class ceiling; pack survivors exactly ----
    {
      unsigned thrUp = rowThr[qidx] | 0x7FFu;
#pragma unroll
      for (int i = 0; i < 16; ++i){
        unsigned b = kb16[i];
        if (b <= thrUp){
          if (selfTile && (i >> 2) == wid && selfR[i & 3]) continue;
          unsigned kb = (b & ~0x7FFu) | (unsigned)(c*64 + (i >> 2)*16 + r0 + (i & 3));
          if (cnt < 6){ buf[cnt*256 + tid] = kb; ++cnt; }
          else ins32(kb, arr);
        }
      }
      for (int t = 0; t < cnt; ++t) ins32(buf[t*256 + tid], arr);
      cnt = 0;
      atomicMin(&rowThr[qidx], arr[19]);
    }

    // ---- write staged regs into the other buffer ----
    if (more){
      unsigned short* BhN = BhA + (cur^1)*BSTR;
      unsigned short* BlN = BlA + (cur^1)*BSTR;
      if (MODE == 1){
        *(short8*)(BhN + tid*8)       = nh0;
        *(short8*)(BhN + (tid+256)*8) = nh1;
        *(short8*)(BlN + tid*8)       = nl0;
        *(short8*)(BlN + (tid+256)*8) = nl1;
      } else {
        if (tid < 64)       *(short8*)(BhN + tid*8)      = nh0;
        else if (tid < 128) *(short8*)(BlN + (tid-64)*8) = nl0;
      }
      if (tid < 64) sqjA[(cur^1)*64 + tid] = nsq;
    }
    __syncthreads();   // next buffer ready; rowThr published; cur reads done
  }
  // ---- merge 4 lane-groups per query -> chunk top-20 ----
  __syncthreads();
  if (g > 0){
#pragma unroll
    for (int t = 0; t < 20; ++t) mD[(qidx*3 + g-1)*20 + t] = arr[t];
  }
  __syncthreads();
  if (g == 0){
    for (int gg = 0; gg < 3; ++gg)
#pragma unroll
      for (int t = 0; t < 20; ++t) ins32(mD[(qidx*3 + gg)*20 + t], arr);
    const size_t gp = gb + rowbase + qidx;
#pragma unroll
    for (int t = 0; t < 20; ++t) pk[((size_t)(ch*20 + t))*NPTS + gp] = arr[t];
  }
}

// ---- merge 2 chunk top-20s -> final idx ----
__global__ __launch_bounds__(256) void knn_merge_k(const unsigned* __restrict__ pk,
                                                   int* __restrict__ idx){
  const int p = blockIdx.x*256 + threadIdx.x;
  double arr[20];
#pragma unroll
  for (int t = 0; t < 20; ++t){
    unsigned k = pk[(size_t)t*NPTS + p];
    unsigned long long K = (((unsigned long long)(k & ~0x7FFu)) << 1) | (k & 0x7FFu);
    arr[t] = __builtin_bit_cast(double, K);
  }
#pragma unroll
  for (int t = 0; t < 20; ++t){
    unsigned k = pk[(size_t)(20 + t)*NPTS + p];
    unsigned long long K = (((unsigned long long)(k & ~0x7FFu)) << 1) | (2048u + (k & 0x7FFu));
    ins64(__builtin_bit_cast(double, K), arr);
  }
  int* o = idx + (size_t)p*KNN_;
#pragma unroll
  for (int t = 0; t < 20; ++t)
    o[t] = (int)(__builtin_bit_cast(unsigned long long, arr[t]) & 0xFFFu);
}

// ------------- EdgeConv1: 6->64->64->64, hi/lo 3-split, fragment-order LDS -------------
__global__ __launch_bounds__(256) void ec1_k(const float* __restrict__ pos, const int* __restrict__ idx1,
    const unsigned short* __restrict__ W1h, const unsigned short* __restrict__ W1l,
    const unsigned short* __restrict__ W2h, const unsigned short* __restrict__ W2l,
    const unsigned short* __restrict__ W3h, const unsigned short* __restrict__ W3l,
    const float* __restrict__ b1, const float* __restrict__ b2, const float* __restrict__ b3,
    unsigned short* __restrict__ x1h, unsigned short* __restrict__ x1l, float* __restrict__ nrm1){
  __shared__ __align__(16) char smem[51200];
  unsigned short* Ah  = (unsigned short*)(smem);            // frag [5][64][8]
  unsigned short* Al  = (unsigned short*)(smem + 5120);
  unsigned short* H1h = (unsigned short*)(smem + 10240);    // frag [5][2][64][8]
  unsigned short* H1l = (unsigned short*)(smem + 20480);
  unsigned short* H2h = (unsigned short*)(smem + 30720);
  unsigned short* H2l = (unsigned short*)(smem + 40960);
  float* dump = (float*)(smem);                             // [80][68] f32 (aliases Ah/Al/H1h, dead)
  const int p0 = blockIdx.x * 4;
  const int bb = p0 >> 12;
  const int tid = threadIdx.x, lane = tid & 63, wid = tid >> 6;
  const int l15 = lane & 15, g = lane >> 4, r0 = g << 2;

  if (tid < 80){ // stage edge features in B-fragment order; zero-fill k>=8
    int p = p0 + tid/20, slot = tid%20;
    int j = idx1[(size_t)p*KNN_ + slot];
    int gj = (bb << 12) + j;
    float a6[6];
    a6[0] = pos[(size_t)p*3]; a6[1] = pos[(size_t)p*3+1]; a6[2] = pos[(size_t)p*3+2];
    a6[3] = pos[(size_t)gj*3]   - a6[0];
    a6[4] = pos[(size_t)gj*3+1] - a6[1];
    a6[5] = pos[(size_t)gj*3+2] - a6[2];
    int mt = tid >> 4, lrow = tid & 15;
    short8 vh, vl, zz = {0,0,0,0,0,0,0,0};
#pragma unroll
    for (int c=0;c<8;++c){
      float v = (c < 6) ? a6[c] : 0.f;
      unsigned short h = f2bf(v);
      vh[c] = (short)h;
      vl[c] = (short)f2bf(v - bf2f(h));
    }
    *(short8*)(Ah + (mt*64 + lrow)*8) = vh;
    *(short8*)(Al + (mt*64 + lrow)*8) = vl;
#pragma unroll
    for (int gg=1;gg<4;++gg){
      *(short8*)(Ah + (mt*64 + gg*16 + lrow)*8) = zz;
      *(short8*)(Al + (mt*64 + gg*16 + lrow)*8) = zz;
    }
  }
  __syncthreads();
  const int nt = wid;
  const int kk2 = nt >> 1, sub2 = (nt & 1)*2 + (g >> 1), e0 = (g & 1)*4;
  { // layer 1 (K=32): A -> H1
    short8 wh = *(const short8*)(W1h + ((size_t)nt*64 + lane)*8);
    short8 wl = *(const short8*)(W1l + ((size_t)nt*64 + lane)*8);
    f32x4 b4 = *(const f32x4*)(b1 + nt*16 + r0);
    for (int mt=0; mt<5; ++mt){
      short8 ah = *(const short8*)(Ah + (mt*64 + lane)*8);
      short8 al = *(const short8*)(Al + (mt*64 + lane)*8);
      f32x4 acc = {0.f,0.f,0.f,0.f};
      acc = mfma16(wh, ah, acc);
      acc = mfma16(wl, ah, acc);
      acc = mfma16(wh, al, acc);
      short4v vh4, vl4;
#pragma unroll
      for (int r=0;r<4;++r){
        float v = fmaxf(acc[r] + b4[r], 0.f);
        unsigned short h = f2bf(v);
        vh4[r] = (short)h;
        vl4[r] = (short)f2bf(v - bf2f(h));
      }
      *(short4v*)(H1h + ((mt*2 + kk2)*64 + sub2*16 + l15)*8 + e0) = vh4;
      *(short4v*)(H1l + ((mt*2 + kk2)*64 + sub2*16 + l15)*8 + e0) = vl4;
    }
  }
  __syncthreads();
  { // layer 2: H1 -> H2
    short8 wh0 = *(const short8*)(W2h + ((size_t)(nt*2+0)*64 + lane)*8);
    short8 wh1 = *(const short8*)(W2h + ((size_t)(nt*2+1)*64 + lane)*8);
    short8 wl0 = *(const short8*)(W2l + ((size_t)(nt*2+0)*64 + lane)*8);
    short8 wl1 = *(const short8*)(W2l + ((size_t)(nt*2+1)*64 + lane)*8);
    f32x4 b4 = *(const f32x4*)(b2 + nt*16 + r0);
    for (int mt=0; mt<5; ++mt){
      short8 ah0 = *(const short8*)(H1h + ((mt*2+0)*64 + lane)*8);
      short8 ah1 = *(const short8*)(H1h + ((mt*2+1)*64 + lane)*8);
      short8 al0 = *(const short8*)(H1l + ((mt*2+0)*64 + lane)*8);
      short8 al1 = *(const short8*)(H1l + ((mt*2+1)*64 + lane)*8);
      f32x4 acc = {0.f,0.f,0.f,0.f};
      acc = mfma16(wh0, ah0, acc); acc = mfma16(wh1, ah1, acc);
      acc = mfma16(wl0, ah0, acc); acc = mfma16(wl1, ah1, acc);
      acc = mfma16(wh0, al0, acc); acc = mfma16(wh1, al1, acc);
      short4v vh4, vl4;
#pragma unroll
      for (int r=0;r<4;++r){
        float v = fmaxf(acc[r] + b4[r], 0.f);
        unsigned short h = f2bf(v);
        vh4[r] = (short)h;
        vl4[r] = (short)f2bf(v - bf2f(h));
      }
      *(short4v*)(H2h + ((mt*2 + kk2)*64 + sub2*16 + l15)*8 + e0) = vh4;
      *(short4v*)(H2l + ((mt*2 + kk2)*64 + sub2*16 + l15)*8 + e0) = vl4;
    }
  }
  __syncthreads();
  { // layer 3: H2 -> f32 dump [80][68]
    short8 wh0 = *(const short8*)(W3h + ((size_t)(nt*2+0)*64 + lane)*8);
    short8 wh1 = *(const short8*)(W3h + ((size_t)(nt*2+1)*64 + lane)*8);
    short8 wl0 = *(const short8*)(W3l + ((size_t)(nt*2+0)*64 + lane)*8);
    short8 wl1 = *(const short8*)(W3l + ((size_t)(nt*2+1)*64 + lane)*8);
    f32x4 b4 = *(const f32x4*)(b3 + nt*16 + r0);
    for (int mt=0; mt<5; ++mt){
      short8 ah0 = *(const short8*)(H2h + ((mt*2+0)*64 + lane)*8);
      short8 ah1 = *(const short8*)(H2h + ((mt*2+1)*64 + lane)*8);
      short8 al0 = *(const short8*)(H2l + ((mt*2+0)*64 + lane)*8);
      short8 al1 = *(const short8*)(H2l + ((mt*2+1)*64 + lane)*8);
      f32x4 acc = {0.f,0.f,0.f,0.f};
      acc = mfma16(wh0, ah0, acc); acc = mfma16(wh1, ah1, acc);
      acc = mfma16(wl0, ah0, acc); acc = mfma16(wl1, ah1, acc);
      acc = mfma16(wh0, al0, acc); acc = mfma16(wh1, al1, acc);
      f32x4 o;
#pragma unroll
      for (int r=0;r<4;++r) o[r] = fmaxf(acc[r] + b4[r], 0.f);
      int edge = mt*16 + l15;
      *(f32x4*)(dump + edge*68 + nt*16 + r0) = o;
    }
  }
  __syncthreads();
  if (tid < 64){ // pool 20 edges per point, 4 channels per thread
    int p = tid >> 4, c4 = tid & 15;
    int st = tid % 20;
    float mx[4] = {0.f,0.f,0.f,0.f};
    for (int e=0;e<20;++e){
      int ee = st + e; if (ee >= 20) ee -= 20;
      f32x4 v = *(const f32x4*)(dump + (p*20 + ee)*68 + c4*4);
#pragma unroll
      for (int r=0;r<4;++r) mx[r] = fmaxf(mx[r], v[r]);
    }
    int gp = p0 + p;
    short4v h4, l4;
    float s = 0.f;
#pragma unroll
    for (int r=0;r<4;++r){
      float m = mx[r];
      unsigned short h = f2bf(m);
      h4[r] = (short)h;
      l4[r] = (short)f2bf(m - bf2f(h));
      s = fmaf(m, m, s);
    }
    *(short4v*)(x1h + (size_t)gp*64 + c4*4) = h4;
    *(short4v*)(x1l + (size_t)gp*64 + c4*4) = l4;
    s += __shfl_xor(s, 1); s += __shfl_xor(s, 2); s += __shfl_xor(s, 4); s += __shfl_xor(s, 8);
    if (c4 == 0) nrm1[gp] = s;
  }
}

// ------------- EdgeConv2: fragment-ordered LDS, swapped-operand MFMA -------------
__global__ __launch_bounds__(256) void ec2_k(const unsigned short* __restrict__ x1h, const int* __restrict__ idx2,
    const unsigned short* __restrict__ V1, const unsigned short* __restrict__ V2, const unsigned short* __restrict__ V3,
    const float* __restrict__ b1, const float* __restrict__ b2, const float* __restrict__ b3,
    unsigned short* __restrict__ x2b){
  __shared__ __align__(16) char smem[81920];
  unsigned short* A  = (unsigned short*)(smem);          // frag [10][4][64][8] 40KB; reused as H2
  unsigned short* H1 = (unsigned short*)(smem + 40960);  // frag 40KB; reused as layer-3 dump
  const int p0 = blockIdx.x * 8, bb = p0 >> 12;
  const int tid = threadIdx.x, lane = tid & 63, wid = tid >> 6;
  const int l15 = lane & 15, r0 = (lane >> 4) << 2;

  if (tid < 160){ // stage edge features in fragment order
    int p = p0 + tid/20, slot = tid%20;
    int j = idx2[(size_t)p*KNN_ + slot];
    int gj = (bb << 12) + j;
    const unsigned short* xi = x1h + (size_t)p*64;
    const unsigned short* xj = x1h + (size_t)gj*64;
    int mt = tid >> 4, lrow = tid & 15;
#pragma unroll
    for (int q=0;q<8;++q){
      short8 vi = *(const short8*)(xi + q*8);
      short8 vj = *(const short8*)(xj + q*8);
      short8 vd;
#pragma unroll
      for (int c=0;c<8;++c) vd[c] = (short)f2bf(bf2fs(vj[c]) - bf2fs(vi[c]));
      *(short8*)(A + (((mt*4 + (q>>2))*64) + (q&3)*16 + lrow)*8) = vi;
      *(short8*)(A + (((mt*4 + 2 + (q>>2))*64) + (q&3)*16 + lrow)*8) = vd;
    }
  }
  __syncthreads();

  { // layer 1: A -> H1
    short8 w[2][4];
#pragma unroll
    for (int ni=0;ni<2;++ni)
#pragma unroll
      for (int kk=0;kk<4;++kk)
        w[ni][kk] = *(const short8*)(V1 + ((size_t)((wid*2+ni)*4+kk)*64 + lane)*8);
    f32x4 b4[2];
    b4[0] = *(const f32x4*)(b1 + (wid*2+0)*16 + r0);
    b4[1] = *(const f32x4*)(b1 + (wid*2+1)*16 + r0);
    for (int mt=0; mt<10; ++mt){
      short8 bfr[4];
#pragma unroll
      for (int kk=0;kk<4;++kk) bfr[kk] = *(const short8*)(A + ((mt*4+kk)*64 + lane)*8);
#pragma unroll
      for (int ni=0;ni<2;++ni){
        int nt = wid*2 + ni;
        f32x4 acc = {0.f,0.f,0.f,0.f};
#pragma unroll
        for (int kk=0;kk<4;++kk) acc = mfma16(w[ni][kk], bfr[kk], acc);
        short4v v4;
#pragma unroll
        for (int r=0;r<4;++r) v4[r] = (short)f2bf(fmaxf(acc[r] + b4[ni][r], 0.f));
        int kk2 = nt >> 1, sub2 = (nt & 1)*2 + (r0 >> 3);
        *(short4v*)(H1 + ((mt*4+kk2)*64 + sub2*16 + l15)*8 + (r0 & 4)) = v4;
      }
    }
  }
  __syncthreads();
  { // layer 2: H1 -> H2 (=A region)
    short8 w[2][4];
#pragma unroll
    for (int ni=0;ni<2;++ni)
#pragma unroll
      for (int kk=0;kk<4;++kk)
        w[ni][kk] = *(const short8*)(V2 + ((size_t)((wid*2+ni)*4+kk)*64 + lane)*8);
    f32x4 b4[2];
    b4[0] = *(const f32x4*)(b2 + (wid*2+0)*16 + r0);
    b4[1] = *(const f32x4*)(b2 + (wid*2+1)*16 + r0);
    for (int mt=0; mt<10; ++mt){
      short8 bfr[4];
#pragma unroll
      for (int kk=0;kk<4;++kk) bfr[kk] = *(const short8*)(H1 + ((mt*4+kk)*64 + lane)*8);
#pragma unroll
      for (int ni=0;ni<2;++ni){
        int nt = wid*2 + ni;
        f32x4 acc = {0.f,0.f,0.f,0.f};
#pragma unroll
        for (int kk=0;kk<4;++kk) acc = mfma16(w[ni][kk], bfr[kk], acc);
        short4v v4;
#pragma unroll
        for (int r=0;r<4;++r) v4[r] = (short)f2bf(fmaxf(acc[r] + b4[ni][r], 0.f));
        int kk2 = nt >> 1, sub2 = (nt & 1)*2 + (r0 >> 3);
        *(short4v*)(A + ((mt*4+kk2)*64 + sub2*16 + l15)*8 + (r0 & 4)) = v4;
      }
    }
  }
  __syncthreads();
  for (int g2=0; g2<2; ++g2){
    {
      short8 w[2][4];
#pragma unroll
      for (int ni=0;ni<2;++ni)
#pragma unroll
        for (int kk=0;kk<4;++kk)
          w[ni][kk] = *(const short8*)(V3 + ((size_t)((g2*8 + wid*2+ni)*4+kk)*64 + lane)*8);
      f32x4 b4[2];
      b4[0] = *(const f32x4*)(b3 + (g2*8 + wid*2+0)*16 + r0);
      b4[1] = *(const f32x4*)(b3 + (g2*8 + wid*2+1)*16 + r0);
      for (int mt=0; mt<10; ++mt){
        short8 bfr[4];
#pragma unroll
        for (int kk=0;kk<4;++kk) bfr[kk] = *(const short8*)(A + ((mt*4+kk)*64 + lane)*8);
#pragma unroll
        for (int ni=0;ni<2;++ni){
          int ntl = wid*2 + ni;
          f32x4 acc = {0.f,0.f,0.f,0.f};
#pragma unroll
          for (int kk=0;kk<4;++kk) acc = mfma16(w[ni][kk], bfr[kk], acc);
          short4v v4;
#pragma unroll
          for (int r=0;r<4;++r) v4[r] = (short)f2bf(fmaxf(acc[r] + b4[ni][r], 0.f));
          int kk2 = ntl >> 1, sub2 = (ntl & 1)*2 + (r0 >> 3);
          *(short4v*)(H1 + ((mt*4+kk2)*64 + sub2*16 + l15)*8 + (r0 & 4)) = v4;
        }
      }
    }
    __syncthreads();
    if (tid < 128){
      int p = tid >> 4, c8 = tid & 15;
      int kk = c8 >> 2, sub = c8 & 3;
      unsigned short mx[8];
#pragma unroll
      for (int e=0;e<8;++e) mx[e] = 0;
      for (int e=0;e<20;++e){
        int ee = e + p + c8; ee -= (ee >= 20) ? 20 : 0; ee -= (ee >= 20) ? 20 : 0;
        int row = p*20 + ee;
        short8 v = *(const short8*)(H1 + (((row>>4)*4 + kk)*64 + sub*16 + (row & 15))*8);
#pragma unroll
        for (int k2=0;k2<8;++k2){
          unsigned short u = (unsigned short)v[k2];
          mx[k2] = u > mx[k2] ? u : mx[k2];
        }
      }
      short8 o;
#pragma unroll
      for (int k2=0;k2<8;++k2) o[k2] = (short)mx[k2];
      *(short8*)(x2b + (size_t)(p0 + p)*256 + g2*128 + c8*8) = o;
    }
    __syncthreads();
  }
}

// ------------- lin0 (256->512) + relu + segment-max into pool -------------
__global__ __launch_bounds__(256) void lin0_k(const unsigned short* __restrict__ x2b, const unsigned short* __restrict__ W0s,
                                              const float* __restrict__ b0, unsigned* __restrict__ pool){
  __shared__ __align__(16) char smem[67584];
  unsigned short* A = (unsigned short*)(smem);        // [128][256] bf16 swizzled
  unsigned* ploc = (unsigned*)(smem + 65536);
  const int blk = blockIdx.x; const size_t row0 = (size_t)blk * 128; const int bb = blk >> 5;
  const int tid = threadIdx.x, lane = tid & 63, wid = tid >> 6;
  for (int it = tid; it < 4096; it += 256){
    int row = it >> 5, q = (it & 31) << 3;
    lds_put8(A, row, q, 256, 7, *(const short8*)(x2b + (row0 + row)*256 + q));
  }
  ploc[tid] = 0u; ploc[tid+256] = 0u;
  __syncthreads();
  const int l15 = lane & 15, kL = (lane >> 4) << 3;
  short8 af[2][8];
#pragma unroll
  for (int m=0;m<2;++m)
#pragma unroll
    for (int kk=0;kk<8;++kk)
      af[m][kk] = lds_frag(A, (wid*2+m)*16 + l15, kk*32 + kL, 256, 7);
  for (int nt=0; nt<32; ++nt){
    f32x4 a0 = {0.f,0.f,0.f,0.f}, a1 = {0.f,0.f,0.f,0.f};
#pragma unroll
    for (int kk=0;kk<8;++kk){
      short8 w = *(const short8*)(W0s + ((size_t)(nt*8+kk)*64 + lane)*8);
      a0 = mfma16(af[0][kk], w, a0);
      a1 = mfma16(af[1][kk], w, a1);
    }
    int col = nt*16 + l15;
    float m = fmaxf(fmaxf(fmaxf(a0[0],a0[1]),fmaxf(a0[2],a0[3])),
                    fmaxf(fmaxf(a1[0],a1[1]),fmaxf(a1[2],a1[3])));
    m = fmaxf(m + b0[col], 0.f);
    atomicMax(&ploc[col], __float_as_uint(m));
  }
  __syncthreads();
  atomicMax(&pool[(size_t)bb*512 + tid], ploc[tid]);
  atomicMax(&pool[(size_t)bb*512 + tid + 256], ploc[tid+256]);
}

// ------------- head: one block per batch row -------------
__global__ __launch_bounds__(256) void head8_k(const unsigned* __restrict__ pool,
    const float* __restrict__ w1, const float* __restrict__ bb1,
    const float* __restrict__ w2, const float* __restrict__ bb2,
    const float* __restrict__ w3, const float* __restrict__ bb3,
    float* __restrict__ out){
  __shared__ float pl[512];
  __shared__ float y1[256];
  __shared__ float y2[256];
  __shared__ float lg[40];
  const int row = blockIdx.x;
  const int tid = threadIdx.x;
  for (int it = tid; it < 512; it += 256) pl[it] = __uint_as_float(pool[row*512 + it]);
  __syncthreads();
  {
    float acc = bb1[tid];
    for (int k=0;k<512;++k) acc = fmaf(pl[k], w1[(size_t)k*256 + tid], acc);
    y1[tid] = fmaxf(acc, 0.f);
  }
  __syncthreads();
  {
    float acc = bb2[tid];
    for (int k=0;k<256;++k) acc = fmaf(y1[k], w2[(size_t)k*256 + tid], acc);
    y2[tid] = fmaxf(acc, 0.f);
  }
  __syncthreads();
  if (tid < 40){
    float acc = bb3[tid];
    for (int k=0;k<256;++k) acc = fmaf(y2[k], w3[(size_t)k*40 + tid], acc);
    lg[tid] = acc;
  }
  __syncthreads();
  if (tid < 40){
    float m = -__builtin_inff();
    for (int c2=0;c2<40;++c2) m = fmaxf(m, lg[c2]);
    float s = 0.f;
    for (int c2=0;c2<40;++c2) s += expf(lg[c2] - m);
    out[row*40 + tid] = lg[tid] - m - logf(s);
  }
}

extern "C" void kernel_launch(void* const* d_in, const int* in_sizes, int n_in,
                              void* d_out, int out_size, void* d_ws, size_t ws_size,
                              hipStream_t stream){
  (void)in_sizes; (void)n_in; (void)out_size; (void)ws_size;
  const float* pos  = (const float*)d_in[0];
  const float* m1w1 = (const float*)d_in[2];  const float* m1b1 = (const float*)d_in[3];
  const float* m1w2 = (const float*)d_in[4];  const float* m1b2 = (const float*)d_in[5];
  const float* m1w3 = (const float*)d_in[6];  const float* m1b3 = (const float*)d_in[7];
  const float* m2w1 = (const float*)d_in[8];  const float* m2b1 = (const float*)d_in[9];
  const float* m2w2 = (const float*)d_in[10]; const float* m2b2 = (const float*)d_in[11];
  const float* m2w3 = (const float*)d_in[12]; const float* m2b3 = (const float*)d_in[13];
  const float* l0w  = (const float*)d_in[14]; const float* l0b  = (const float*)d_in[15];
  const float* l1w  = (const float*)d_in[16]; const float* l1b  = (const float*)d_in[17];
  const float* l2w  = (const float*)d_in[18]; const float* l2b  = (const float*)d_in[19];
  const float* l3w  = (const float*)d_in[20]; const float* l3b  = (const float*)d_in[21];

  char* ws = (char*)d_ws;
  size_t o = 0;
  auto alloc = [&](size_t bytes){ size_t r = o; o += (bytes + 255) & ~(size_t)255; return r; };
  size_t o_idx1 = alloc((size_t)NPTS*20*4);
  size_t o_idx2 = alloc((size_t)NPTS*20*4);
  size_t o_x1h  = alloc((size_t)NPTS*64*2);
  size_t o_x1l  = alloc((size_t)NPTS*64*2);
  size_t o_nrm  = alloc((size_t)NPTS*4);
  size_t o_x2b  = alloc((size_t)NPTS*256*2);
  size_t o_pool = alloc(8*512*4);
  size_t o_p3h  = alloc((size_t)NPTS*8*2);
  size_t o_p3l  = alloc((size_t)NPTS*8*2);
  size_t o_nrm3 = alloc((size_t)NPTS*4);
  size_t o_pk   = alloc((size_t)2*20*NPTS*4);
  size_t o_W1h = alloc(4*1*64*8*2),  o_W1l = alloc(4*1*64*8*2);
  size_t o_W2h = alloc(4*2*64*8*2),  o_W2l = alloc(4*2*64*8*2);
  size_t o_W3h = alloc(4*2*64*8*2),  o_W3l = alloc(4*2*64*8*2);
  size_t o_V1  = alloc(8*4*64*8*2);
  size_t o_V2  = alloc(8*4*64*8*2);
  size_t o_V3  = alloc(16*4*64*8*2);
  size_t o_W0  = alloc(32*8*64*8*2);

  hipMemsetAsync(ws + o_pool, 0, 8*512*4, stream);

  stage_all_k<<<229,256,0,stream>>>(pos,
      (unsigned short*)(ws+o_p3h), (unsigned short*)(ws+o_p3l), (float*)(ws+o_nrm3),
      m1w1, m1w2, m1w3, m2w1, m2w2, m2w3, l0w,
      (unsigned short*)(ws+o_W1h), (unsigned short*)(ws+o_W1l),
      (unsigned short*)(ws+o_W2h), (unsigned short*)(ws+o_W2l),
      (unsigned short*)(ws+o_W3h), (unsigned short*)(ws+o_W3l),
      (unsigned short*)(ws+o_V1), (unsigned short*)(ws+o_V2), (unsigned short*)(ws+o_V3),
      (unsigned short*)(ws+o_W0));

  knn_k<0><<<1024,256,0,stream>>>((const unsigned short*)(ws+o_p3h), (const unsigned short*)(ws+o_p3l),
                                  (const float*)(ws+o_nrm3), (unsigned*)(ws+o_pk));
  knn_merge_k<<<128,256,0,stream>>>((const unsigned*)(ws+o_pk), (int*)(ws+o_idx1));

  ec1_k<<<8192,256,0,stream>>>(pos, (const int*)(ws+o_idx1),
      (const unsigned short*)(ws+o_W1h), (const unsigned short*)(ws+o_W1l),
      (const unsigned short*)(ws+o_W2h), (const unsigned short*)(ws+o_W2l),
      (const unsigned short*)(ws+o_W3h), (const unsigned short*)(ws+o_W3l),
      m1b1, m1b2, m1b3,
      (unsigned short*)(ws+o_x1h), (unsigned short*)(ws+o_x1l), (float*)(ws+o_nrm));

  knn_k<1><<<1024,256,0,stream>>>((const unsigned short*)(ws+o_x1h), (const unsigned short*)(ws+o_x1l),
                                  (const float*)(ws+o_nrm), (unsigned*)(ws+o_pk));
  knn_merge_k<<<128,256,0,stream>>>((const unsigned*)(ws+o_pk), (int*)(ws+o_idx2));

  ec2_k<<<4096,256,0,stream>>>((const unsigned short*)(ws+o_x1h), (const int*)(ws+o_idx2),
      (const unsigned short*)(ws+o_V1), (const unsigned short*)(ws+o_V2), (const unsigned short*)(ws+o_V3),
      m2b1, m2b2, m2b3, (unsigned short*)(ws+o_x2b));

  lin0_k<<<256,256,0,stream>>>((const unsigned short*)(ws+o_x2b), (const unsigned short*)(ws+o_W0),
                               l0b, (unsigned*)(ws+o_pool));

  head8_k<<<8,256,0,stream>>>((const unsigned*)(ws+o_pool), l1w, l1b, l2w, l2b, l3w, l3b, (float*)d_out);
}